// Round 5
// baseline (388.504 us; speedup 1.0000x reference)
//
#include <hip/hip_runtime.h>
#include <hip/hip_cooperative_groups.h>
#include <hip/hip_fp16.h>
#include <math.h>

namespace cg = cooperative_groups;

#define N_NODES 100000
#define N_EDGES 1600000
#define IN_F    128
#define OUT_F   64
#define K_BKT     196                            // dst buckets of 512 nodes
#define BKT_SHIFT 9
#define BKT_NODES 512
#define BKT_CAP   10240                          // slots per bucket (E=8192, +22 sigma)
#define CHUNK     4096                           // partition block edge count
#define PBLKS     ((N_EDGES + CHUNK - 1) / CHUNK)          // 391
#define LTILES    (N_NODES / 16)                 // 6250 exact 16-row MFMA tiles
#define MEGA_BLKS 256                            // 1 block/CU co-resident (coop)
#define MEGA_THR  1024

typedef _Float16 half8 __attribute__((ext_vector_type(8)));
typedef float    f32x4 __attribute__((ext_vector_type(4)));

// ---------------- workspace layout (4-byte units) ----------------
// fth      : N_NODES*OUT_F/2       (fp16 projected features, 12.8 MB)
// staging  : K_BKT*BKT_CAP uint    (packed src|dloc<<17, capacity layout, 8 MB)
// edge_src : K_BKT*BKT_CAP int     (CSR src ids, capacity layout, 8 MB)
// bcursor  : K_BKT                 (zeroed by hipMemsetAsync)
// row_beg/row_end : N_NODES each

// ONE cooperative dispatch for all preprocessing. Diagnostic rationale:
// rounds 0-4 held the non-fused time at 137+-2.5 us across four completely
// different middle-stage structures, while roofline says ~25 us of work.
// Collapsing partition|linear -> grid.sync -> place into a single dispatch
// either removes inter-dispatch overhead (total ~105) or produces a single
// big dispatch whose counters finally show where the time goes.
//   phase 1a: grid-stride in-LDS counting sort of 4096-edge chunks into
//             bucket regions at b*BKT_CAP (reservation atomics on bcursor).
//   phase 1b: grid-stride MFMA fp16 linear, wave = 16-row tile of feat @ W
//             (direct W scalar loads: L1-hot, shown equivalent to WT in r2/r3).
//   grid.sync (device fence)
//   phase 2:  place, one block per bucket: counts + 512-scan -> row_beg/
//             row_end, scatter src ids into exact CSR slots (LDS reused).
__global__ __launch_bounds__(MEGA_THR, 4) void mega_kernel(const int* __restrict__ src,
                                                           const int* __restrict__ dst,
                                                           int* __restrict__ bcursor,
                                                           unsigned* __restrict__ staging,
                                                           const float* __restrict__ feat,
                                                           const float* __restrict__ W,
                                                           __half* __restrict__ fth,
                                                           int* __restrict__ row_beg,
                                                           int* __restrict__ row_end,
                                                           int* __restrict__ edge_src) {
    __shared__ int hist[256], lbase[256], gbase[256], sc[256];
    __shared__ unsigned sval[CHUNK];
    __shared__ int spos[CHUNK];
    int t = threadIdx.x;

    // ---- phase 1a: partition chunks (grid-stride, block-uniform) ----
    for (int c = blockIdx.x; c < PBLKS; c += MEGA_BLKS) {
        if (t < 256) hist[t] = 0;
        __syncthreads();
        int beg = c * CHUNK;
        int end = min(beg + CHUNK, N_EDGES);
        for (int i = beg + t; i < end; i += MEGA_THR)
            atomicAdd(&hist[dst[i] >> BKT_SHIFT], 1);
        __syncthreads();
        if (t < 256) sc[t] = hist[t];
        __syncthreads();
        for (int off = 1; off < 256; off <<= 1) {
            int add = (t >= off && t < 256) ? sc[t - off] : 0;
            __syncthreads();
            if (t < 256) sc[t] += add;
            __syncthreads();
        }
        if (t < 256) {
            int v = hist[t];
            lbase[t] = sc[t] - v;                // block-local exclusive
            if (t < K_BKT && v) gbase[t] = t * BKT_CAP + atomicAdd(&bcursor[t], v);
            hist[t] = 0;                         // reuse as rank counter
        }
        __syncthreads();
        for (int i = beg + t; i < end; i += MEGA_THR) {
            int s = src[i], d = dst[i];
            int b = d >> BKT_SHIFT;
            int r = atomicAdd(&hist[b], 1);
            int lp = lbase[b] + r;
            sval[lp] = (unsigned)s | ((unsigned)(d & (BKT_NODES - 1)) << 17);
            spos[lp] = gbase[b] + r;
        }
        __syncthreads();
        int n = end - beg;
        for (int p = t; p < n; p += MEGA_THR) staging[spos[p]] = sval[p];
        __syncthreads();
    }

    // ---- phase 1b: MFMA linear (grid-stride waves; no LDS, no deps) ----
    {
        int lane = t & 63;
        int m = lane & 15, kg = lane >> 4;
        int nw = MEGA_BLKS * (MEGA_THR / 64);
        for (int gwave = blockIdx.x * (MEGA_THR / 64) + (t >> 6); gwave < LTILES; gwave += nw) {
            int r0 = gwave * 16;
            // B fragments: B[k][n], n = lane&15, k = kb*32 + kg*8 + j (W L1-hot)
            half8 fb[4][4];
#pragma unroll
            for (int kb = 0; kb < 4; ++kb)
#pragma unroll
                for (int nb = 0; nb < 4; ++nb) {
                    const float* wp = W + (size_t)(kb * 32 + kg * 8) * OUT_F + nb * 16 + m;
#pragma unroll
                    for (int j = 0; j < 8; ++j)
                        fb[kb][nb][j] = (_Float16)wp[j * OUT_F];
                }
            f32x4 acc[4];
#pragma unroll
            for (int nb = 0; nb < 4; ++nb) acc[nb] = (f32x4){0.f, 0.f, 0.f, 0.f};
#pragma unroll
            for (int kb = 0; kb < 4; ++kb) {
                const float4* ap = (const float4*)(feat + (size_t)(r0 + m) * IN_F + kb * 32 + kg * 8);
                float4 a0 = ap[0], a1 = ap[1];
                half8 fa = {(_Float16)a0.x, (_Float16)a0.y, (_Float16)a0.z, (_Float16)a0.w,
                            (_Float16)a1.x, (_Float16)a1.y, (_Float16)a1.z, (_Float16)a1.w};
#pragma unroll
                for (int nb = 0; nb < 4; ++nb)
                    acc[nb] = __builtin_amdgcn_mfma_f32_16x16x32_f16(fa, fb[kb][nb], acc[nb], 0, 0, 0);
            }
            // D: col = lane&15, row = (lane>>4)*4 + i
#pragma unroll
            for (int nb = 0; nb < 4; ++nb)
#pragma unroll
                for (int i = 0; i < 4; ++i)
                    fth[(size_t)(r0 + kg * 4 + i) * OUT_F + nb * 16 + m] = __float2half_rn(acc[nb][i]);
        }
    }

    __threadfence();                              // device-scope release (XCD L2s)
    cg::this_grid().sync();

    // ---- phase 2: place (LDS reused from spos region) ----
    {
        int* cnt  = spos;
        int* psc  = spos + BKT_NODES;
        int* lcur = spos + 2 * BKT_NODES;
        for (int b = blockIdx.x; b < K_BKT; b += MEGA_BLKS) {
            if (t < BKT_NODES) cnt[t] = 0;
            __syncthreads();
            int base = b * BKT_CAP;
            int n = bcursor[b];
            for (int i = t; i < n; i += MEGA_THR)
                atomicAdd(&cnt[staging[base + i] >> 17], 1);
            __syncthreads();
            if (t < BKT_NODES) psc[t] = cnt[t];
            __syncthreads();
            for (int off = 1; off < BKT_NODES; off <<= 1) {
                int add = (t >= off && t < BKT_NODES) ? psc[t - off] : 0;
                __syncthreads();
                if (t < BKT_NODES) psc[t] += add;
                __syncthreads();
            }
            if (t < BKT_NODES) {
                int v = cnt[t];
                int b0 = base + psc[t] - v;
                lcur[t] = b0;
                int node = b * BKT_NODES + t;
                if (node < N_NODES) { row_beg[node] = b0; row_end[node] = b0 + v; }
            }
            __syncthreads();
            for (int i = base + t; i < base + n; i += MEGA_THR) {
                unsigned u = staging[i];
                int pos = atomicAdd(&lcur[u >> 17], 1);
                edge_src[pos] = (int)(u & 0x1FFFFu);
            }
            __syncthreads();
        }
    }
}

// one wave per dst node; 16 lanes/edge (4 fp16 channels/lane), 16 edges in
// flight (4 chains per quarter). Scores computed directly in log2 domain by
// pre-scaling the dst fragment with log2(e); one softmax rescale per 16
// edges. Invalid slots score -1e30 -> weight exp2()==0.  (UNCHANGED, 65 us)
__global__ __launch_bounds__(256) void fused_node_kernel(const __half* __restrict__ fth,
                                                         const int* __restrict__ row_beg,
                                                         const int* __restrict__ row_end,
                                                         const int* __restrict__ edge_src,
                                                         float* __restrict__ out) {
    const float LOG2E = 1.44269504088896340736f;
    int wave = (blockIdx.x * 256 + threadIdx.x) >> 6;
    int lane = threadIdx.x & 63;
    if (wave >= N_NODES) return;
    int q = lane >> 4, ql = lane & 15;

    int beg = row_beg[wave];
    int end = row_end[wave];

    float2 rd = *(const float2*)(fth + (size_t)wave * OUT_F + 4 * ql);
    __half2 d01 = *(__half2*)&rd.x, d23 = *(__half2*)&rd.y;
    float fd0 = __half2float(d01.x) * LOG2E, fd1 = __half2float(d01.y) * LOG2E;
    float fd2 = __half2float(d23.x) * LOG2E, fd3 = __half2float(d23.y) * LOG2E;

    float m = -1e30f, l = 0.f;
    float a0 = 0.f, a1 = 0.f, a2 = 0.f, a3 = 0.f;

    for (int i = beg; i < end; i += 16) {
        int e0 = i + q, e1 = e0 + 4, e2 = e0 + 8, e3 = e0 + 12;
        bool u0 = e0 < end, u1 = e1 < end, u2 = e2 < end, u3 = e3 < end;
        int s0 = edge_src[u0 ? e0 : beg];
        int s1 = edge_src[u1 ? e1 : beg];
        int s2 = edge_src[u2 ? e2 : beg];
        int s3 = edge_src[u3 ? e3 : beg];
        float2 r0 = *(const float2*)(fth + (size_t)s0 * OUT_F + 4 * ql);
        float2 r1 = *(const float2*)(fth + (size_t)s1 * OUT_F + 4 * ql);
        float2 r2 = *(const float2*)(fth + (size_t)s2 * OUT_F + 4 * ql);
        float2 r3 = *(const float2*)(fth + (size_t)s3 * OUT_F + 4 * ql);
        __half2 A01 = *(__half2*)&r0.x, A23 = *(__half2*)&r0.y;
        __half2 B01 = *(__half2*)&r1.x, B23 = *(__half2*)&r1.y;
        __half2 C01 = *(__half2*)&r2.x, C23 = *(__half2*)&r2.y;
        __half2 D01 = *(__half2*)&r3.x, D23 = *(__half2*)&r3.y;
        float vA0 = __half2float(A01.x), vA1 = __half2float(A01.y);
        float vA2 = __half2float(A23.x), vA3 = __half2float(A23.y);
        float vB0 = __half2float(B01.x), vB1 = __half2float(B01.y);
        float vB2 = __half2float(B23.x), vB3 = __half2float(B23.y);
        float vC0 = __half2float(C01.x), vC1 = __half2float(C01.y);
        float vC2 = __half2float(C23.x), vC3 = __half2float(C23.y);
        float vD0 = __half2float(D01.x), vD1 = __half2float(D01.y);
        float vD2 = __half2float(D23.x), vD3 = __half2float(D23.y);

        float p0 = vA0 * fd0 + vA1 * fd1 + vA2 * fd2 + vA3 * fd3;
        float p1 = vB0 * fd0 + vB1 * fd1 + vB2 * fd2 + vB3 * fd3;
        float p2 = vC0 * fd0 + vC1 * fd1 + vC2 * fd2 + vC3 * fd3;
        float p3 = vD0 * fd0 + vD1 * fd1 + vD2 * fd2 + vD3 * fd3;
#pragma unroll
        for (int dd = 1; dd < 16; dd <<= 1) {
            p0 += __shfl_xor(p0, dd);
            p1 += __shfl_xor(p1, dd);
            p2 += __shfl_xor(p2, dd);
            p3 += __shfl_xor(p3, dd);
        }
        if (!u0) p0 = -1e30f;
        if (!u1) p1 = -1e30f;
        if (!u2) p2 = -1e30f;
        if (!u3) p3 = -1e30f;
        float nm = fmaxf(fmaxf(fmaxf(p0, p1), fmaxf(p2, p3)), m);
        float alpha = exp2f(m - nm);
        float w0 = exp2f(p0 - nm), w1 = exp2f(p1 - nm);
        float w2 = exp2f(p2 - nm), w3 = exp2f(p3 - nm);
        l = l * alpha + ((w0 + w1) + (w2 + w3));
        a0 = a0 * alpha + (w0 * vA0 + w1 * vB0) + (w2 * vC0 + w3 * vD0);
        a1 = a1 * alpha + (w0 * vA1 + w1 * vB1) + (w2 * vC1 + w3 * vD1);
        a2 = a2 * alpha + (w0 * vA2 + w1 * vB2) + (w2 * vC2 + w3 * vD2);
        a3 = a3 * alpha + (w0 * vA3 + w1 * vB3) + (w2 * vC3 + w3 * vD3);
        m = nm;
    }

    // merge the 4 quarter-states (xor16, then xor32) in log2 domain
#pragma unroll
    for (int dd = 16; dd <= 32; dd <<= 1) {
        float m2 = __shfl_xor(m, dd), l2 = __shfl_xor(l, dd);
        float b0 = __shfl_xor(a0, dd), b1 = __shfl_xor(a1, dd);
        float b2 = __shfl_xor(a2, dd), b3 = __shfl_xor(a3, dd);
        float M = fmaxf(m, m2);
        float e1 = exp2f(m - M), e2 = exp2f(m2 - M);
        l = l * e1 + l2 * e2;
        a0 = a0 * e1 + b0 * e2;
        a1 = a1 * e1 + b1 * e2;
        a2 = a2 * e1 + b2 * e2;
        a3 = a3 * e1 + b3 * e2;
        m = M;
    }
    if (q == 0) {
        float inv = (l > 0.f) ? 1.f / l : 0.f;
        *(float4*)(out + (size_t)wave * OUT_F + 4 * ql) =
            make_float4(a0 * inv, a1 * inv, a2 * inv, a3 * inv);
    }
}

extern "C" void kernel_launch(void* const* d_in, const int* in_sizes, int n_in,
                              void* d_out, int out_size, void* d_ws, size_t ws_size,
                              hipStream_t stream) {
    const float* feat = (const float*)d_in[0];
    const float* W    = (const float*)d_in[1];
    const int*   src  = (const int*)d_in[2];
    const int*   dst  = (const int*)d_in[3];
    float* out = (float*)d_out;

    __half*   fth      = (__half*)d_ws;
    unsigned* staging  = (unsigned*)((int*)d_ws + (size_t)N_NODES * OUT_F / 2);
    int*      edge_src = (int*)(staging + (size_t)K_BKT * BKT_CAP);
    int*      bcursor  = edge_src + (size_t)K_BKT * BKT_CAP;
    int*      row_beg  = bcursor + K_BKT;
    int*      row_end  = row_beg + N_NODES;

    (void)hipMemsetAsync(bcursor, 0, K_BKT * sizeof(int), stream);
    void* kargs[] = {(void*)&src, (void*)&dst, (void*)&bcursor, (void*)&staging,
                     (void*)&feat, (void*)&W, (void*)&fth,
                     (void*)&row_beg, (void*)&row_end, (void*)&edge_src};
    (void)hipLaunchCooperativeKernel((const void*)mega_kernel, dim3(MEGA_BLKS), dim3(MEGA_THR),
                                     kargs, 0, stream);
    fused_node_kernel<<<(N_NODES * 64) / 256, 256, 0, stream>>>(fth, row_beg, row_end, edge_src, out);
}

// Round 6
// 332.518 us; speedup vs baseline: 1.1684x; 1.1684x over previous
//
#include <hip/hip_runtime.h>
#include <hip/hip_fp16.h>
#include <math.h>

#define N_NODES 100000
#define N_EDGES 1600000
#define IN_F    128
#define OUT_F   64
#define CHUNK     4096                           // edges per block in edge-loop kernels
#define EBLKS     ((N_EDGES + CHUNK - 1) / CHUNK)          // 391
#define LTILES    (N_NODES / 16)                 // 6250 exact 16-row MFMA tiles
#define LIN_BLKS  ((LTILES + 15) / 16)           // 391 (16 waves/block @1024 thr)
#define SC_BLKS   ((N_NODES + 1023) / 1024)      // 98 scan blocks

typedef _Float16 half8 __attribute__((ext_vector_type(8)));
typedef float    f32x4 __attribute__((ext_vector_type(4)));

// ---------------- workspace layout (4-byte units) ----------------
// fth      : N_NODES*OUT_F/2   fp16 projected features (12.8 MB)
// edge_src : N_EDGES           CSR src ids, exact-fit (6.4 MB)
// deg      : N_NODES           per-node in-degree   (zeroed by memset)
// gcur     : 1                 global CSR allocator (zeroed by same memset)
// row_beg/row_end/cursor : N_NODES each
//
// r5 post-mortem: the LDS counting-sort CSR build ran at 1.5% VALU / 3% HBM
// for 253 us — pure barrier/LDS-atomic serialization. Replaced with the
// minimal atomic CSR build: degree atomics -> block-allocated scan ->
// scatter atomics. No staging array, no edge-wide scans, no grid.sync.

// K1: blocks [0,LIN_BLKS) = MFMA fp16 linear (wave = 16-row tile of feat@W);
//     blocks [LIN_BLKS,..) = degree count, 1.6M fire-and-forget L2 atomics.
__global__ __launch_bounds__(1024) void linear_degree_kernel(const int* __restrict__ dst,
                                                             int* __restrict__ deg,
                                                             const float* __restrict__ feat,
                                                             const float* __restrict__ W,
                                                             __half* __restrict__ fth) {
    int t = threadIdx.x;
    if (blockIdx.x >= LIN_BLKS) {
        int beg = (blockIdx.x - LIN_BLKS) * CHUNK;
        int end = min(beg + CHUNK, N_EDGES);
        for (int i = beg + t; i < end; i += 1024)
            atomicAdd(&deg[dst[i]], 1);
        return;
    }
    // ---- MFMA linear: one wave per 16-row tile, 16 waves/block ----
    int gwave = blockIdx.x * 16 + (t >> 6);
    if (gwave >= LTILES) return;
    int lane = t & 63;
    int m = lane & 15, kg = lane >> 4;
    int r0 = gwave * 16;

    // B fragments: B[k][n], n = lane&15, k = kb*32 + kg*8 + j (W 32 KB, L1-hot)
    half8 fb[4][4];
#pragma unroll
    for (int kb = 0; kb < 4; ++kb)
#pragma unroll
        for (int nb = 0; nb < 4; ++nb) {
            const float* wp = W + (size_t)(kb * 32 + kg * 8) * OUT_F + nb * 16 + m;
#pragma unroll
            for (int j = 0; j < 8; ++j)
                fb[kb][nb][j] = (_Float16)wp[j * OUT_F];
        }

    f32x4 acc[4];
#pragma unroll
    for (int nb = 0; nb < 4; ++nb) acc[nb] = (f32x4){0.f, 0.f, 0.f, 0.f};

#pragma unroll
    for (int kb = 0; kb < 4; ++kb) {
        const float4* ap = (const float4*)(feat + (size_t)(r0 + m) * IN_F + kb * 32 + kg * 8);
        float4 a0 = ap[0], a1 = ap[1];
        half8 fa = {(_Float16)a0.x, (_Float16)a0.y, (_Float16)a0.z, (_Float16)a0.w,
                    (_Float16)a1.x, (_Float16)a1.y, (_Float16)a1.z, (_Float16)a1.w};
#pragma unroll
        for (int nb = 0; nb < 4; ++nb)
            acc[nb] = __builtin_amdgcn_mfma_f32_16x16x32_f16(fa, fb[kb][nb], acc[nb], 0, 0, 0);
    }
    // D: col = lane&15, row = (lane>>4)*4 + i
#pragma unroll
    for (int nb = 0; nb < 4; ++nb)
#pragma unroll
        for (int i = 0; i < 4; ++i)
            fth[(size_t)(r0 + kg * 4 + i) * OUT_F + nb * 16 + m] = __float2half_rn(acc[nb][i]);
}

// K2: CSR offset allocation. Block-local 1024-wide scan of degrees; ONE
// atomicAdd(gcur, block_total) allocates the block's contiguous range —
// no inter-block ordering needed (row placement in edge_src is arbitrary).
__global__ __launch_bounds__(1024) void scan_kernel(const int* __restrict__ deg,
                                                    int* __restrict__ gcur,
                                                    int* __restrict__ row_beg,
                                                    int* __restrict__ row_end,
                                                    int* __restrict__ cursor) {
    __shared__ int s[1024];
    __shared__ int base;
    int t = threadIdx.x;
    int node = blockIdx.x * 1024 + t;
    int d = (node < N_NODES) ? deg[node] : 0;
    s[t] = d;
    __syncthreads();
    for (int off = 1; off < 1024; off <<= 1) {
        int add = (t >= off) ? s[t - off] : 0;
        __syncthreads();
        s[t] += add;
        __syncthreads();
    }
    if (t == 1023) base = atomicAdd(gcur, s[1023]);
    __syncthreads();
    if (node < N_NODES) {
        int b = base + s[t] - d;                 // exclusive within block + block base
        row_beg[node] = b;
        row_end[node] = b + d;
        cursor[node]  = b;
    }
}

// K3: scatter src ids into CSR slots. 1.6M atomic-with-return on 100K
// cursors (~16 contention each), latency-hidden by 391x1024 threads.
__global__ __launch_bounds__(1024) void scatter_kernel(const int* __restrict__ src,
                                                       const int* __restrict__ dst,
                                                       int* __restrict__ cursor,
                                                       int* __restrict__ edge_src) {
    int t = threadIdx.x;
    int beg = blockIdx.x * CHUNK;
    int end = min(beg + CHUNK, N_EDGES);
    for (int i = beg + t; i < end; i += 1024) {
        int pos = atomicAdd(&cursor[dst[i]], 1);
        edge_src[pos] = src[i];
    }
}

// one wave per dst node; 16 lanes/edge (4 fp16 channels/lane), 16 edges in
// flight (4 chains per quarter). Scores computed directly in log2 domain by
// pre-scaling the dst fragment with log2(e); one softmax rescale per 16
// edges. Invalid slots score -1e30 -> weight exp2()==0.  (UNCHANGED, 65 us)
__global__ __launch_bounds__(256) void fused_node_kernel(const __half* __restrict__ fth,
                                                         const int* __restrict__ row_beg,
                                                         const int* __restrict__ row_end,
                                                         const int* __restrict__ edge_src,
                                                         float* __restrict__ out) {
    const float LOG2E = 1.44269504088896340736f;
    int wave = (blockIdx.x * 256 + threadIdx.x) >> 6;
    int lane = threadIdx.x & 63;
    if (wave >= N_NODES) return;
    int q = lane >> 4, ql = lane & 15;

    int beg = row_beg[wave];
    int end = row_end[wave];

    float2 rd = *(const float2*)(fth + (size_t)wave * OUT_F + 4 * ql);
    __half2 d01 = *(__half2*)&rd.x, d23 = *(__half2*)&rd.y;
    float fd0 = __half2float(d01.x) * LOG2E, fd1 = __half2float(d01.y) * LOG2E;
    float fd2 = __half2float(d23.x) * LOG2E, fd3 = __half2float(d23.y) * LOG2E;

    float m = -1e30f, l = 0.f;
    float a0 = 0.f, a1 = 0.f, a2 = 0.f, a3 = 0.f;

    for (int i = beg; i < end; i += 16) {
        int e0 = i + q, e1 = e0 + 4, e2 = e0 + 8, e3 = e0 + 12;
        bool u0 = e0 < end, u1 = e1 < end, u2 = e2 < end, u3 = e3 < end;
        int s0 = edge_src[u0 ? e0 : beg];
        int s1 = edge_src[u1 ? e1 : beg];
        int s2 = edge_src[u2 ? e2 : beg];
        int s3 = edge_src[u3 ? e3 : beg];
        float2 r0 = *(const float2*)(fth + (size_t)s0 * OUT_F + 4 * ql);
        float2 r1 = *(const float2*)(fth + (size_t)s1 * OUT_F + 4 * ql);
        float2 r2 = *(const float2*)(fth + (size_t)s2 * OUT_F + 4 * ql);
        float2 r3 = *(const float2*)(fth + (size_t)s3 * OUT_F + 4 * ql);
        __half2 A01 = *(__half2*)&r0.x, A23 = *(__half2*)&r0.y;
        __half2 B01 = *(__half2*)&r1.x, B23 = *(__half2*)&r1.y;
        __half2 C01 = *(__half2*)&r2.x, C23 = *(__half2*)&r2.y;
        __half2 D01 = *(__half2*)&r3.x, D23 = *(__half2*)&r3.y;
        float vA0 = __half2float(A01.x), vA1 = __half2float(A01.y);
        float vA2 = __half2float(A23.x), vA3 = __half2float(A23.y);
        float vB0 = __half2float(B01.x), vB1 = __half2float(B01.y);
        float vB2 = __half2float(B23.x), vB3 = __half2float(B23.y);
        float vC0 = __half2float(C01.x), vC1 = __half2float(C01.y);
        float vC2 = __half2float(C23.x), vC3 = __half2float(C23.y);
        float vD0 = __half2float(D01.x), vD1 = __half2float(D01.y);
        float vD2 = __half2float(D23.x), vD3 = __half2float(D23.y);

        float p0 = vA0 * fd0 + vA1 * fd1 + vA2 * fd2 + vA3 * fd3;
        float p1 = vB0 * fd0 + vB1 * fd1 + vB2 * fd2 + vB3 * fd3;
        float p2 = vC0 * fd0 + vC1 * fd1 + vC2 * fd2 + vC3 * fd3;
        float p3 = vD0 * fd0 + vD1 * fd1 + vD2 * fd2 + vD3 * fd3;
#pragma unroll
        for (int dd = 1; dd < 16; dd <<= 1) {
            p0 += __shfl_xor(p0, dd);
            p1 += __shfl_xor(p1, dd);
            p2 += __shfl_xor(p2, dd);
            p3 += __shfl_xor(p3, dd);
        }
        if (!u0) p0 = -1e30f;
        if (!u1) p1 = -1e30f;
        if (!u2) p2 = -1e30f;
        if (!u3) p3 = -1e30f;
        float nm = fmaxf(fmaxf(fmaxf(p0, p1), fmaxf(p2, p3)), m);
        float alpha = exp2f(m - nm);
        float w0 = exp2f(p0 - nm), w1 = exp2f(p1 - nm);
        float w2 = exp2f(p2 - nm), w3 = exp2f(p3 - nm);
        l = l * alpha + ((w0 + w1) + (w2 + w3));
        a0 = a0 * alpha + (w0 * vA0 + w1 * vB0) + (w2 * vC0 + w3 * vD0);
        a1 = a1 * alpha + (w0 * vA1 + w1 * vB1) + (w2 * vC1 + w3 * vD1);
        a2 = a2 * alpha + (w0 * vA2 + w1 * vB2) + (w2 * vC2 + w3 * vD2);
        a3 = a3 * alpha + (w0 * vA3 + w1 * vB3) + (w2 * vC3 + w3 * vD3);
        m = nm;
    }

    // merge the 4 quarter-states (xor16, then xor32) in log2 domain
#pragma unroll
    for (int dd = 16; dd <= 32; dd <<= 1) {
        float m2 = __shfl_xor(m, dd), l2 = __shfl_xor(l, dd);
        float b0 = __shfl_xor(a0, dd), b1 = __shfl_xor(a1, dd);
        float b2 = __shfl_xor(a2, dd), b3 = __shfl_xor(a3, dd);
        float M = fmaxf(m, m2);
        float e1 = exp2f(m - M), e2 = exp2f(m2 - M);
        l = l * e1 + l2 * e2;
        a0 = a0 * e1 + b0 * e2;
        a1 = a1 * e1 + b1 * e2;
        a2 = a2 * e1 + b2 * e2;
        a3 = a3 * e1 + b3 * e2;
        m = M;
    }
    if (q == 0) {
        float inv = (l > 0.f) ? 1.f / l : 0.f;
        *(float4*)(out + (size_t)wave * OUT_F + 4 * ql) =
            make_float4(a0 * inv, a1 * inv, a2 * inv, a3 * inv);
    }
}

extern "C" void kernel_launch(void* const* d_in, const int* in_sizes, int n_in,
                              void* d_out, int out_size, void* d_ws, size_t ws_size,
                              hipStream_t stream) {
    const float* feat = (const float*)d_in[0];
    const float* W    = (const float*)d_in[1];
    const int*   src  = (const int*)d_in[2];
    const int*   dst  = (const int*)d_in[3];
    float* out = (float*)d_out;

    __half* fth      = (__half*)d_ws;
    int*    edge_src = (int*)d_ws + (size_t)N_NODES * OUT_F / 2;
    int*    deg      = edge_src + N_EDGES;
    int*    gcur     = deg + N_NODES;            // memset covers deg+gcur
    int*    row_beg  = gcur + 1;
    int*    row_end  = row_beg + N_NODES;
    int*    cursor   = row_end + N_NODES;

    (void)hipMemsetAsync(deg, 0, (N_NODES + 1) * sizeof(int), stream);
    linear_degree_kernel<<<LIN_BLKS + EBLKS, 1024, 0, stream>>>(dst, deg, feat, W, fth);
    scan_kernel<<<SC_BLKS, 1024, 0, stream>>>(deg, gcur, row_beg, row_end, cursor);
    scatter_kernel<<<EBLKS, 1024, 0, stream>>>(src, dst, cursor, edge_src);
    fused_node_kernel<<<(N_NODES * 64) / 256, 256, 0, stream>>>(fth, row_beg, row_end, edge_src, out);
}

// Round 7
// 194.981 us; speedup vs baseline: 1.9925x; 1.7054x over previous
//
#include <hip/hip_runtime.h>
#include <hip/hip_fp16.h>
#include <math.h>

#define N_NODES 100000
#define N_EDGES 1600000
#define IN_F    128
#define OUT_F   64
#define K_BKT     196                            // dst buckets of 512 nodes
#define BKT_SHIFT 9
#define BKT_NODES 512
#define BKT_CAP   10240                          // slots per bucket region (E~8163, +23 sigma)
#define CHUNK     4096                           // partition block edge count
#define PBLKS     ((N_EDGES + CHUNK - 1) / CHUNK)          // 391
#define LTILES    (N_NODES / 16)                 // 6250 exact 16-row MFMA tiles
#define LBLKS     ((LTILES + 3) / 4)             // 1563 (4 waves/block)

typedef _Float16 half8 __attribute__((ext_vector_type(8)));
typedef float    f32x4 __attribute__((ext_vector_type(4)));

// ---------------- workspace layout (4-byte units) ----------------
// fth      : N_NODES*OUT_F/2   fp16 projected features (12.8 MB)
// staging  : PBLKS*CHUNK uint  bucket-sorted edges, SLICE-contiguous per block
// edge_src : K_BKT*BKT_CAP     CSR src ids, capacity layout (8 MB)
// pcnt     : PBLKS*256         per-block per-bucket counts
// pbase    : PBLKS*256         per-block per-bucket exclusive offsets
// row_beg/row_end : N_NODES
//
// r6 post-mortem: totals decompose as kernel-true-time + ~20us per dispatch
// of launch/drain gap; global atomic scatter wrote 107 MB (full-line HBM RMW
// per 4B write). This version: 3 dispatches, no memset, no global atomics,
// all scatter writes either slice-contiguous (K1) or 40KB-bucket-local (K2).

// K1: blocks [0,PBLKS): in-LDS counting sort of a 4096-edge chunk, dumped
//     CONTIGUOUSLY into the block's own staging slice (fully coalesced,
//     full-line writes); per-bucket counts/offsets to pcnt/pbase.
//     blocks [PBLKS,..): MFMA fp16 linear — wave = 16-row tile of feat @ W.
__global__ __launch_bounds__(256) void partition_linear_kernel(const int* __restrict__ src,
                                                               const int* __restrict__ dst,
                                                               unsigned* __restrict__ staging,
                                                               int* __restrict__ pcnt,
                                                               int* __restrict__ pbase,
                                                               const float* __restrict__ feat,
                                                               const float* __restrict__ W,
                                                               __half* __restrict__ fth) {
    __shared__ int hist[256], lbase[256], sc[256];
    __shared__ unsigned sval[CHUNK];
    int t = threadIdx.x;
    if (blockIdx.x < PBLKS) {
        hist[t] = 0;
        __syncthreads();
        int beg = blockIdx.x * CHUNK;
        int end = min(beg + CHUNK, N_EDGES);
        for (int i = beg + t; i < end; i += 256)
            atomicAdd(&hist[dst[i] >> BKT_SHIFT], 1);
        __syncthreads();
        int v = hist[t];
        sc[t] = v;
        __syncthreads();
        for (int off = 1; off < 256; off <<= 1) {
            int add = (t >= off) ? sc[t - off] : 0;
            __syncthreads();
            sc[t] += add;
            __syncthreads();
        }
        int lb = sc[t] - v;                      // block-local exclusive
        lbase[t] = lb;
        pcnt[blockIdx.x * 256 + t]  = v;         // unconditional: replay-safe
        pbase[blockIdx.x * 256 + t] = lb;
        hist[t] = 0;                             // reuse as rank counter
        __syncthreads();
        for (int i = beg + t; i < end; i += 256) {
            int s = src[i], d = dst[i];
            int b = d >> BKT_SHIFT;
            int r = atomicAdd(&hist[b], 1);
            sval[lbase[b] + r] = (unsigned)s | ((unsigned)(d & (BKT_NODES - 1)) << 17);
        }
        __syncthreads();
        int n = end - beg;
        for (int p = t; p < n; p += 256)
            staging[(size_t)blockIdx.x * CHUNK + p] = sval[p];
        return;
    }
    // ---- MFMA linear: one wave per 16-row tile ----
    int gwave = (blockIdx.x - PBLKS) * 4 + (t >> 6);
    if (gwave >= LTILES) return;
    int lane = t & 63;
    int m = lane & 15, kg = lane >> 4;
    int r0 = gwave * 16;

    // B fragments: B[k][n], n = lane&15, k = kb*32 + kg*8 + j (W 32 KB, L1-hot)
    half8 fb[4][4];
#pragma unroll
    for (int kb = 0; kb < 4; ++kb)
#pragma unroll
        for (int nb = 0; nb < 4; ++nb) {
            const float* wp = W + (size_t)(kb * 32 + kg * 8) * OUT_F + nb * 16 + m;
#pragma unroll
            for (int j = 0; j < 8; ++j)
                fb[kb][nb][j] = (_Float16)wp[j * OUT_F];
        }

    f32x4 acc[4];
#pragma unroll
    for (int nb = 0; nb < 4; ++nb) acc[nb] = (f32x4){0.f, 0.f, 0.f, 0.f};

#pragma unroll
    for (int kb = 0; kb < 4; ++kb) {
        const float4* ap = (const float4*)(feat + (size_t)(r0 + m) * IN_F + kb * 32 + kg * 8);
        float4 a0 = ap[0], a1 = ap[1];
        half8 fa = {(_Float16)a0.x, (_Float16)a0.y, (_Float16)a0.z, (_Float16)a0.w,
                    (_Float16)a1.x, (_Float16)a1.y, (_Float16)a1.z, (_Float16)a1.w};
#pragma unroll
        for (int nb = 0; nb < 4; ++nb)
            acc[nb] = __builtin_amdgcn_mfma_f32_16x16x32_f16(fa, fb[kb][nb], acc[nb], 0, 0, 0);
    }
    // D: col = lane&15, row = (lane>>4)*4 + i
#pragma unroll
    for (int nb = 0; nb < 4; ++nb)
#pragma unroll
        for (int i = 0; i < 4; ++i)
            fth[(size_t)(r0 + kg * 4 + i) * OUT_F + nb * 16 + m] = __float2half_rn(acc[nb][i]);
}

// K2: one block per bucket. Segment table from pcnt/pbase column b (391
// gathers + 512-wide LDS scan), 9-step binary search locates each slot's
// segment; edges gathered into LDS (one coalesced pass, fused with node
// counting). Node scan -> row_beg/row_end; scatter into the bucket's own
// 40KB edge_src region (L2-local: no partial-line HBM amplification).
__global__ __launch_bounds__(1024) void place_kernel(const unsigned* __restrict__ staging,
                                                     const int* __restrict__ pcnt,
                                                     const int* __restrict__ pbase,
                                                     int* __restrict__ row_beg,
                                                     int* __restrict__ row_end,
                                                     int* __restrict__ edge_src) {
    __shared__ unsigned sbuf[BKT_CAP];
    __shared__ int exo[PBLKS];                   // exclusive segment offsets
    __shared__ int pbs[PBLKS];
    __shared__ int s512[512];
    __shared__ int cnt[BKT_NODES], lcur[BKT_NODES];
    __shared__ int ntot;
    int t = threadIdx.x;
    int b = blockIdx.x;

    int d = 0;
    if (t < PBLKS) { d = pcnt[t * 256 + b]; pbs[t] = pbase[t * 256 + b]; }
    if (t < 512) { s512[t] = (t < PBLKS) ? d : 0; cnt[t] = 0; }
    __syncthreads();
    for (int off = 1; off < 512; off <<= 1) {
        int add = (t >= off && t < 512) ? s512[t - off] : 0;
        __syncthreads();
        if (t < 512) s512[t] += add;
        __syncthreads();
    }
    if (t < PBLKS) exo[t] = s512[t] - d;
    if (t == PBLKS - 1) ntot = s512[t];
    __syncthreads();
    int n = ntot;

    // gather + per-node count in one pass (thread i owns slot i)
    for (int i = t; i < n; i += 1024) {
        int lo = 0, hi = PBLKS - 1;
        while (lo < hi) {                        // last j with exo[j] <= i
            int mid = (lo + hi + 1) >> 1;
            if (exo[mid] <= i) lo = mid; else hi = mid - 1;
        }
        unsigned u = staging[(size_t)lo * CHUNK + pbs[lo] + (i - exo[lo])];
        sbuf[i] = u;
        atomicAdd(&cnt[u >> 17], 1);
    }
    __syncthreads();
    int v = (t < 512) ? cnt[t] : 0;
    if (t < 512) s512[t] = v;
    __syncthreads();
    for (int off = 1; off < 512; off <<= 1) {
        int add = (t >= off && t < 512) ? s512[t - off] : 0;
        __syncthreads();
        if (t < 512) s512[t] += add;
        __syncthreads();
    }
    if (t < 512) {
        int b0 = b * BKT_CAP + s512[t] - v;
        lcur[t] = b0;
        int node = b * BKT_NODES + t;
        if (node < N_NODES) { row_beg[node] = b0; row_end[node] = b0 + v; }
    }
    __syncthreads();
    for (int i = t; i < n; i += 1024) {
        unsigned u = sbuf[i];
        int pos = atomicAdd(&lcur[u >> 17], 1);
        edge_src[pos] = (int)(u & 0x1FFFFu);
    }
}

// one wave per dst node; 16 lanes/edge (4 fp16 channels/lane), 16 edges in
// flight (4 chains per quarter). Scores computed directly in log2 domain by
// pre-scaling the dst fragment with log2(e); one softmax rescale per 16
// edges. Invalid slots score -1e30 -> weight exp2()==0.  (UNCHANGED, 65 us)
__global__ __launch_bounds__(256) void fused_node_kernel(const __half* __restrict__ fth,
                                                         const int* __restrict__ row_beg,
                                                         const int* __restrict__ row_end,
                                                         const int* __restrict__ edge_src,
                                                         float* __restrict__ out) {
    const float LOG2E = 1.44269504088896340736f;
    int wave = (blockIdx.x * 256 + threadIdx.x) >> 6;
    int lane = threadIdx.x & 63;
    if (wave >= N_NODES) return;
    int q = lane >> 4, ql = lane & 15;

    int beg = row_beg[wave];
    int end = row_end[wave];

    float2 rd = *(const float2*)(fth + (size_t)wave * OUT_F + 4 * ql);
    __half2 d01 = *(__half2*)&rd.x, d23 = *(__half2*)&rd.y;
    float fd0 = __half2float(d01.x) * LOG2E, fd1 = __half2float(d01.y) * LOG2E;
    float fd2 = __half2float(d23.x) * LOG2E, fd3 = __half2float(d23.y) * LOG2E;

    float m = -1e30f, l = 0.f;
    float a0 = 0.f, a1 = 0.f, a2 = 0.f, a3 = 0.f;

    for (int i = beg; i < end; i += 16) {
        int e0 = i + q, e1 = e0 + 4, e2 = e0 + 8, e3 = e0 + 12;
        bool u0 = e0 < end, u1 = e1 < end, u2 = e2 < end, u3 = e3 < end;
        int s0 = edge_src[u0 ? e0 : beg];
        int s1 = edge_src[u1 ? e1 : beg];
        int s2 = edge_src[u2 ? e2 : beg];
        int s3 = edge_src[u3 ? e3 : beg];
        float2 r0 = *(const float2*)(fth + (size_t)s0 * OUT_F + 4 * ql);
        float2 r1 = *(const float2*)(fth + (size_t)s1 * OUT_F + 4 * ql);
        float2 r2 = *(const float2*)(fth + (size_t)s2 * OUT_F + 4 * ql);
        float2 r3 = *(const float2*)(fth + (size_t)s3 * OUT_F + 4 * ql);
        __half2 A01 = *(__half2*)&r0.x, A23 = *(__half2*)&r0.y;
        __half2 B01 = *(__half2*)&r1.x, B23 = *(__half2*)&r1.y;
        __half2 C01 = *(__half2*)&r2.x, C23 = *(__half2*)&r2.y;
        __half2 D01 = *(__half2*)&r3.x, D23 = *(__half2*)&r3.y;
        float vA0 = __half2float(A01.x), vA1 = __half2float(A01.y);
        float vA2 = __half2float(A23.x), vA3 = __half2float(A23.y);
        float vB0 = __half2float(B01.x), vB1 = __half2float(B01.y);
        float vB2 = __half2float(B23.x), vB3 = __half2float(B23.y);
        float vC0 = __half2float(C01.x), vC1 = __half2float(C01.y);
        float vC2 = __half2float(C23.x), vC3 = __half2float(C23.y);
        float vD0 = __half2float(D01.x), vD1 = __half2float(D01.y);
        float vD2 = __half2float(D23.x), vD3 = __half2float(D23.y);

        float p0 = vA0 * fd0 + vA1 * fd1 + vA2 * fd2 + vA3 * fd3;
        float p1 = vB0 * fd0 + vB1 * fd1 + vB2 * fd2 + vB3 * fd3;
        float p2 = vC0 * fd0 + vC1 * fd1 + vC2 * fd2 + vC3 * fd3;
        float p3 = vD0 * fd0 + vD1 * fd1 + vD2 * fd2 + vD3 * fd3;
#pragma unroll
        for (int dd = 1; dd < 16; dd <<= 1) {
            p0 += __shfl_xor(p0, dd);
            p1 += __shfl_xor(p1, dd);
            p2 += __shfl_xor(p2, dd);
            p3 += __shfl_xor(p3, dd);
        }
        if (!u0) p0 = -1e30f;
        if (!u1) p1 = -1e30f;
        if (!u2) p2 = -1e30f;
        if (!u3) p3 = -1e30f;
        float nm = fmaxf(fmaxf(fmaxf(p0, p1), fmaxf(p2, p3)), m);
        float alpha = exp2f(m - nm);
        float w0 = exp2f(p0 - nm), w1 = exp2f(p1 - nm);
        float w2 = exp2f(p2 - nm), w3 = exp2f(p3 - nm);
        l = l * alpha + ((w0 + w1) + (w2 + w3));
        a0 = a0 * alpha + (w0 * vA0 + w1 * vB0) + (w2 * vC0 + w3 * vD0);
        a1 = a1 * alpha + (w0 * vA1 + w1 * vB1) + (w2 * vC1 + w3 * vD1);
        a2 = a2 * alpha + (w0 * vA2 + w1 * vB2) + (w2 * vC2 + w3 * vD2);
        a3 = a3 * alpha + (w0 * vA3 + w1 * vB3) + (w2 * vC3 + w3 * vD3);
        m = nm;
    }

    // merge the 4 quarter-states (xor16, then xor32) in log2 domain
#pragma unroll
    for (int dd = 16; dd <= 32; dd <<= 1) {
        float m2 = __shfl_xor(m, dd), l2 = __shfl_xor(l, dd);
        float b0 = __shfl_xor(a0, dd), b1 = __shfl_xor(a1, dd);
        float b2 = __shfl_xor(a2, dd), b3 = __shfl_xor(a3, dd);
        float M = fmaxf(m, m2);
        float e1 = exp2f(m - M), e2 = exp2f(m2 - M);
        l = l * e1 + l2 * e2;
        a0 = a0 * e1 + b0 * e2;
        a1 = a1 * e1 + b1 * e2;
        a2 = a2 * e1 + b2 * e2;
        a3 = a3 * e1 + b3 * e2;
        m = M;
    }
    if (q == 0) {
        float inv = (l > 0.f) ? 1.f / l : 0.f;
        *(float4*)(out + (size_t)wave * OUT_F + 4 * ql) =
            make_float4(a0 * inv, a1 * inv, a2 * inv, a3 * inv);
    }
}

extern "C" void kernel_launch(void* const* d_in, const int* in_sizes, int n_in,
                              void* d_out, int out_size, void* d_ws, size_t ws_size,
                              hipStream_t stream) {
    const float* feat = (const float*)d_in[0];
    const float* W    = (const float*)d_in[1];
    const int*   src  = (const int*)d_in[2];
    const int*   dst  = (const int*)d_in[3];
    float* out = (float*)d_out;

    __half*   fth      = (__half*)d_ws;
    unsigned* staging  = (unsigned*)((int*)d_ws + (size_t)N_NODES * OUT_F / 2);
    int*      edge_src = (int*)(staging + (size_t)PBLKS * CHUNK);
    int*      pcnt     = edge_src + (size_t)K_BKT * BKT_CAP;
    int*      pbase    = pcnt + PBLKS * 256;
    int*      row_beg  = pbase + PBLKS * 256;
    int*      row_end  = row_beg + N_NODES;

    partition_linear_kernel<<<PBLKS + LBLKS, 256, 0, stream>>>(src, dst, staging, pcnt, pbase,
                                                               feat, W, fth);
    place_kernel<<<K_BKT, 1024, 0, stream>>>(staging, pcnt, pbase, row_beg, row_end, edge_src);
    fused_node_kernel<<<(N_NODES * 64) / 256, 256, 0, stream>>>(fth, row_beg, row_end, edge_src, out);
}

// Round 8
// 188.793 us; speedup vs baseline: 2.0578x; 1.0328x over previous
//
#include <hip/hip_runtime.h>
#include <hip/hip_fp16.h>
#include <math.h>

#define N_NODES 100000
#define N_EDGES 1600000
#define IN_F    128
#define OUT_F   64
#define K_BKT     196                            // dst buckets of 512 nodes
#define BKT_SHIFT 9
#define BKT_NODES 512
#define BKT_CAP   10240                          // slots per bucket region (E~8163, +23 sigma)
#define CHUNK     4096                           // partition block edge count
#define PBLKS     ((N_EDGES + CHUNK - 1) / CHUNK)          // 391
#define LTILES    (N_NODES / 16)                 // 6250 exact 16-row MFMA tiles
#define LBLKS     ((LTILES + 3) / 4)             // 1563 (4 waves/block)

typedef _Float16 half8 __attribute__((ext_vector_type(8)));
typedef _Float16 h2 __attribute__((ext_vector_type(2)));
typedef _Float16 h4 __attribute__((ext_vector_type(4)));
typedef __fp16   q2v __attribute__((ext_vector_type(2)));
typedef float    f32x4 __attribute__((ext_vector_type(4)));

// f16 pair-dot with f32 accumulate (v_dot2_f32_f16); scalar fallback if absent.
__device__ __forceinline__ float fdot2f(h2 a, h2 b, float c) {
#if __has_builtin(__builtin_amdgcn_fdot2)
    return __builtin_amdgcn_fdot2(__builtin_bit_cast(q2v, a), __builtin_bit_cast(q2v, b), c, false);
#else
    return (float)a[0] * (float)b[0] + (float)a[1] * (float)b[1] + c;
#endif
}

// one v_add_f32_dpp step of a 16-lane xor-reduce (ctrl must be a literal)
#if __has_builtin(__builtin_amdgcn_update_dpp)
#define DPP_ADD(x, ctrl)                                                                  \
    (x) += __builtin_bit_cast(float, __builtin_amdgcn_update_dpp(                         \
               0, __builtin_bit_cast(int, (x)), (ctrl), 0xF, 0xF, true))
// xor1 = quad_perm[1,0,3,2]=0xB1; xor2 = quad_perm[2,3,0,1]=0x4E;
// xor4 ~ row_half_mirror(0x141) and xor8 ~ row_mirror(0x140): valid because
// after the first two steps each 4-/8-lane group is value-uniform.
#define REDUCE16(x) do { DPP_ADD(x, 0xB1); DPP_ADD(x, 0x4E); \
                         DPP_ADD(x, 0x141); DPP_ADD(x, 0x140); } while (0)
#else
#define REDUCE16(x) do { x += __shfl_xor(x, 1); x += __shfl_xor(x, 2); \
                         x += __shfl_xor(x, 4); x += __shfl_xor(x, 8); } while (0)
#endif

// ---------------- workspace layout (4-byte units) ----------------
// fth      : N_NODES*OUT_F/2   fp16 projected features (12.8 MB)
// staging  : PBLKS*CHUNK uint  bucket-sorted edges, SLICE-contiguous per block
// edge_src : K_BKT*BKT_CAP     CSR src ids, capacity layout (8 MB)
// pcnt     : PBLKS*256         per-block per-bucket counts
// pbase    : PBLKS*256         per-block per-bucket exclusive offsets
// row_beg/row_end : N_NODES

// K1: blocks [0,PBLKS): in-LDS counting sort of a 4096-edge chunk, dumped
//     CONTIGUOUSLY into the block's own staging slice; counts to pcnt/pbase.
//     blocks [PBLKS,..): MFMA fp16 linear — wave = 16-row tile of feat @ W.
__global__ __launch_bounds__(256) void partition_linear_kernel(const int* __restrict__ src,
                                                               const int* __restrict__ dst,
                                                               unsigned* __restrict__ staging,
                                                               int* __restrict__ pcnt,
                                                               int* __restrict__ pbase,
                                                               const float* __restrict__ feat,
                                                               const float* __restrict__ W,
                                                               __half* __restrict__ fth) {
    __shared__ int hist[256], lbase[256], sc[256];
    __shared__ unsigned sval[CHUNK];
    int t = threadIdx.x;
    if (blockIdx.x < PBLKS) {
        hist[t] = 0;
        __syncthreads();
        int beg = blockIdx.x * CHUNK;
        int end = min(beg + CHUNK, N_EDGES);
        for (int i = beg + t; i < end; i += 256)
            atomicAdd(&hist[dst[i] >> BKT_SHIFT], 1);
        __syncthreads();
        int v = hist[t];
        sc[t] = v;
        __syncthreads();
        for (int off = 1; off < 256; off <<= 1) {
            int add = (t >= off) ? sc[t - off] : 0;
            __syncthreads();
            sc[t] += add;
            __syncthreads();
        }
        int lb = sc[t] - v;                      // block-local exclusive
        lbase[t] = lb;
        pcnt[blockIdx.x * 256 + t]  = v;
        pbase[blockIdx.x * 256 + t] = lb;
        hist[t] = 0;                             // reuse as rank counter
        __syncthreads();
        for (int i = beg + t; i < end; i += 256) {
            int s = src[i], d = dst[i];
            int b = d >> BKT_SHIFT;
            int r = atomicAdd(&hist[b], 1);
            sval[lbase[b] + r] = (unsigned)s | ((unsigned)(d & (BKT_NODES - 1)) << 17);
        }
        __syncthreads();
        int n = end - beg;
        for (int p = t; p < n; p += 256)
            staging[(size_t)blockIdx.x * CHUNK + p] = sval[p];
        return;
    }
    // ---- MFMA linear: one wave per 16-row tile ----
    int gwave = (blockIdx.x - PBLKS) * 4 + (t >> 6);
    if (gwave >= LTILES) return;
    int lane = t & 63;
    int m = lane & 15, kg = lane >> 4;
    int r0 = gwave * 16;

    half8 fb[4][4];
#pragma unroll
    for (int kb = 0; kb < 4; ++kb)
#pragma unroll
        for (int nb = 0; nb < 4; ++nb) {
            const float* wp = W + (size_t)(kb * 32 + kg * 8) * OUT_F + nb * 16 + m;
#pragma unroll
            for (int j = 0; j < 8; ++j)
                fb[kb][nb][j] = (_Float16)wp[j * OUT_F];
        }

    f32x4 acc[4];
#pragma unroll
    for (int nb = 0; nb < 4; ++nb) acc[nb] = (f32x4){0.f, 0.f, 0.f, 0.f};

#pragma unroll
    for (int kb = 0; kb < 4; ++kb) {
        const float4* ap = (const float4*)(feat + (size_t)(r0 + m) * IN_F + kb * 32 + kg * 8);
        float4 a0 = ap[0], a1 = ap[1];
        half8 fa = {(_Float16)a0.x, (_Float16)a0.y, (_Float16)a0.z, (_Float16)a0.w,
                    (_Float16)a1.x, (_Float16)a1.y, (_Float16)a1.z, (_Float16)a1.w};
#pragma unroll
        for (int nb = 0; nb < 4; ++nb)
            acc[nb] = __builtin_amdgcn_mfma_f32_16x16x32_f16(fa, fb[kb][nb], acc[nb], 0, 0, 0);
    }
#pragma unroll
    for (int nb = 0; nb < 4; ++nb)
#pragma unroll
        for (int i = 0; i < 4; ++i)
            fth[(size_t)(r0 + kg * 4 + i) * OUT_F + nb * 16 + m] = __float2half_rn(acc[nb][i]);
}

// K2: one block per bucket. Segment table from pcnt/pbase column b + 512-wide
// LDS scan; WAVE-PER-SEGMENT contiguous gather into LDS (replaces r7's
// per-element 9-step dependent binary search: 391 wave-copies vs 8163
// serial LDS search chains). Then per-node count/scan -> row_beg/row_end,
// scatter into the bucket's own 40KB edge_src region (L2-local writes).
__global__ __launch_bounds__(1024) void place_kernel(const unsigned* __restrict__ staging,
                                                     const int* __restrict__ pcnt,
                                                     const int* __restrict__ pbase,
                                                     int* __restrict__ row_beg,
                                                     int* __restrict__ row_end,
                                                     int* __restrict__ edge_src) {
    __shared__ unsigned sbuf[BKT_CAP];
    __shared__ int exo[PBLKS];                   // exclusive segment offsets
    __shared__ int pbs[PBLKS];
    __shared__ int scnt[PBLKS];
    __shared__ int s512[512];
    __shared__ int cnt[BKT_NODES], lcur[BKT_NODES];
    __shared__ int ntot;
    int t = threadIdx.x;
    int b = blockIdx.x;

    int d = 0;
    if (t < PBLKS) { d = pcnt[t * 256 + b]; pbs[t] = pbase[t * 256 + b]; scnt[t] = d; }
    if (t < 512) { s512[t] = (t < PBLKS) ? d : 0; cnt[t] = 0; }
    __syncthreads();
    for (int off = 1; off < 512; off <<= 1) {
        int add = (t >= off && t < 512) ? s512[t - off] : 0;
        __syncthreads();
        if (t < 512) s512[t] += add;
        __syncthreads();
    }
    if (t < PBLKS) exo[t] = s512[t] - d;
    if (t == PBLKS - 1) ntot = s512[t];
    __syncthreads();
    int n = ntot;

    // wave-per-segment gather: wave w copies segments w, w+16, ... (~21 elems each)
    {
        int wid = t >> 6, ln = t & 63;
        for (int s = wid; s < PBLKS; s += 16) {
            int c = scnt[s], eo = exo[s];
            size_t gb = (size_t)s * CHUNK + pbs[s];
            for (int j = ln; j < c; j += 64)
                sbuf[eo + j] = staging[gb + j];
        }
    }
    __syncthreads();
    for (int i = t; i < n; i += 1024)
        atomicAdd(&cnt[sbuf[i] >> 17], 1);
    __syncthreads();
    int v = (t < 512) ? cnt[t] : 0;
    if (t < 512) s512[t] = v;
    __syncthreads();
    for (int off = 1; off < 512; off <<= 1) {
        int add = (t >= off && t < 512) ? s512[t - off] : 0;
        __syncthreads();
        if (t < 512) s512[t] += add;
        __syncthreads();
    }
    if (t < 512) {
        int b0 = b * BKT_CAP + s512[t] - v;
        lcur[t] = b0;
        int node = b * BKT_NODES + t;
        if (node < N_NODES) { row_beg[node] = b0; row_end[node] = b0 + v; }
    }
    __syncthreads();
    for (int i = t; i < n; i += 1024) {
        unsigned u = sbuf[i];
        int pos = atomicAdd(&lcur[u >> 17], 1);
        edge_src[pos] = (int)(u & 0x1FFFFu);
    }
}

// one wave per dst node; 16 lanes/edge (4 fp16 channels/lane), 16 edges in
// flight. v2: scores and weighted accumulation via v_dot2_f32_f16 (f16 pair
// ops, f32 accumulate — removes all per-edge cvt_f32_f16 and halves the FMA
// count); 16-lane reduce via fused DPP adds. Per-quarter online softmax in
// log2 domain; degree-0 quarters keep m=-1e30 so the epilogue merge zeroes
// their junk contributions (same invariant as v1).
__global__ __launch_bounds__(256) void fused_node_kernel(const __half* __restrict__ fth,
                                                         const int* __restrict__ row_beg,
                                                         const int* __restrict__ row_end,
                                                         const int* __restrict__ edge_src,
                                                         float* __restrict__ out) {
    const float LOG2E = 1.44269504088896340736f;
    int wave = (blockIdx.x * 256 + threadIdx.x) >> 6;
    int lane = threadIdx.x & 63;
    if (wave >= N_NODES) return;
    int q = lane >> 4, ql = lane & 15;

    int beg = row_beg[wave];
    int end = row_end[wave];

    const _Float16* fh = (const _Float16*)fth;
    h4 rdv = *(const h4*)(fh + (size_t)wave * OUT_F + 4 * ql);
    h2 dlo = __builtin_shufflevector(rdv, rdv, 0, 1);
    h2 dhi = __builtin_shufflevector(rdv, rdv, 2, 3);

    float m = -1e30f, l = 0.f;
    float a0 = 0.f, a1 = 0.f, a2 = 0.f, a3 = 0.f;

    for (int i = beg; i < end; i += 16) {
        int e0 = i + q, e1 = e0 + 4, e2 = e0 + 8, e3 = e0 + 12;
        bool u0 = e0 < end, u1 = e1 < end, u2 = e2 < end, u3 = e3 < end;
        int s0 = edge_src[u0 ? e0 : beg];
        int s1 = edge_src[u1 ? e1 : beg];
        int s2 = edge_src[u2 ? e2 : beg];
        int s3 = edge_src[u3 ? e3 : beg];
        h4 rA = *(const h4*)(fh + (size_t)s0 * OUT_F + 4 * ql);
        h4 rB = *(const h4*)(fh + (size_t)s1 * OUT_F + 4 * ql);
        h4 rC = *(const h4*)(fh + (size_t)s2 * OUT_F + 4 * ql);
        h4 rD = *(const h4*)(fh + (size_t)s3 * OUT_F + 4 * ql);

        float p0 = fdot2f(__builtin_shufflevector(rA, rA, 0, 1), dlo,
                   fdot2f(__builtin_shufflevector(rA, rA, 2, 3), dhi, 0.f));
        float p1 = fdot2f(__builtin_shufflevector(rB, rB, 0, 1), dlo,
                   fdot2f(__builtin_shufflevector(rB, rB, 2, 3), dhi, 0.f));
        float p2 = fdot2f(__builtin_shufflevector(rC, rC, 0, 1), dlo,
                   fdot2f(__builtin_shufflevector(rC, rC, 2, 3), dhi, 0.f));
        float p3 = fdot2f(__builtin_shufflevector(rD, rD, 0, 1), dlo,
                   fdot2f(__builtin_shufflevector(rD, rD, 2, 3), dhi, 0.f));
        REDUCE16(p0);
        REDUCE16(p1);
        REDUCE16(p2);
        REDUCE16(p3);
        p0 = u0 ? p0 * LOG2E : -1e30f;
        p1 = u1 ? p1 * LOG2E : -1e30f;
        p2 = u2 ? p2 * LOG2E : -1e30f;
        p3 = u3 ? p3 * LOG2E : -1e30f;

        float nm = fmaxf(fmaxf(fmaxf(p0, p1), fmaxf(p2, p3)), m);
        float alpha = exp2f(m - nm);
        float w0 = exp2f(p0 - nm), w1 = exp2f(p1 - nm);
        float w2 = exp2f(p2 - nm), w3 = exp2f(p3 - nm);
        l = l * alpha + ((w0 + w1) + (w2 + w3));
#if __has_builtin(__builtin_amdgcn_cvt_pkrtz)
        h2 wlo = __builtin_bit_cast(h2, __builtin_amdgcn_cvt_pkrtz(w0, w1));
        h2 whi = __builtin_bit_cast(h2, __builtin_amdgcn_cvt_pkrtz(w2, w3));
#else
        h2 wlo = {(_Float16)w0, (_Float16)w1};
        h2 whi = {(_Float16)w2, (_Float16)w3};
#endif
        h2 cab0 = {rA[0], rB[0]}, ccd0 = {rC[0], rD[0]};
        h2 cab1 = {rA[1], rB[1]}, ccd1 = {rC[1], rD[1]};
        h2 cab2 = {rA[2], rB[2]}, ccd2 = {rC[2], rD[2]};
        h2 cab3 = {rA[3], rB[3]}, ccd3 = {rC[3], rD[3]};
        a0 = fdot2f(wlo, cab0, fdot2f(whi, ccd0, a0 * alpha));
        a1 = fdot2f(wlo, cab1, fdot2f(whi, ccd1, a1 * alpha));
        a2 = fdot2f(wlo, cab2, fdot2f(whi, ccd2, a2 * alpha));
        a3 = fdot2f(wlo, cab3, fdot2f(whi, ccd3, a3 * alpha));
        m = nm;
    }

    // merge the 4 quarter-states (xor16, then xor32) in log2 domain
#pragma unroll
    for (int dd = 16; dd <= 32; dd <<= 1) {
        float m2 = __shfl_xor(m, dd), l2 = __shfl_xor(l, dd);
        float b0 = __shfl_xor(a0, dd), b1 = __shfl_xor(a1, dd);
        float b2 = __shfl_xor(a2, dd), b3 = __shfl_xor(a3, dd);
        float M = fmaxf(m, m2);
        float e1 = exp2f(m - M), e2 = exp2f(m2 - M);
        l = l * e1 + l2 * e2;
        a0 = a0 * e1 + b0 * e2;
        a1 = a1 * e1 + b1 * e2;
        a2 = a2 * e1 + b2 * e2;
        a3 = a3 * e1 + b3 * e2;
        m = M;
    }
    if (q == 0) {
        float inv = (l > 0.f) ? 1.f / l : 0.f;
        *(float4*)(out + (size_t)wave * OUT_F + 4 * ql) =
            make_float4(a0 * inv, a1 * inv, a2 * inv, a3 * inv);
    }
}

extern "C" void kernel_launch(void* const* d_in, const int* in_sizes, int n_in,
                              void* d_out, int out_size, void* d_ws, size_t ws_size,
                              hipStream_t stream) {
    const float* feat = (const float*)d_in[0];
    const float* W    = (const float*)d_in[1];
    const int*   src  = (const int*)d_in[2];
    const int*   dst  = (const int*)d_in[3];
    float* out = (float*)d_out;

    __half*   fth      = (__half*)d_ws;
    unsigned* staging  = (unsigned*)((int*)d_ws + (size_t)N_NODES * OUT_F / 2);
    int*      edge_src = (int*)(staging + (size_t)PBLKS * CHUNK);
    int*      pcnt     = edge_src + (size_t)K_BKT * BKT_CAP;
    int*      pbase    = pcnt + PBLKS * 256;
    int*      row_beg  = pbase + PBLKS * 256;
    int*      row_end  = row_beg + N_NODES;

    partition_linear_kernel<<<PBLKS + LBLKS, 256, 0, stream>>>(src, dst, staging, pcnt, pbase,
                                                               feat, W, fth);
    place_kernel<<<K_BKT, 1024, 0, stream>>>(staging, pcnt, pbase, row_beg, row_end, edge_src);
    fused_node_kernel<<<(N_NODES * 64) / 256, 256, 0, stream>>>(fth, row_beg, row_end, edge_src, out);
}